// Round 8
// baseline (1674.595 us; speedup 1.0000x reference)
//
#include <hip/hip_runtime.h>
#include <hip/hip_bf16.h>
#include <cstdint>

// HeteroGAT on MI355X.
// CSR build: range-partitioned (8 node-ranges ~ 8 XCDs) direct count + fill —
// all writes to a given cnt/fillpos/csr region come from blocks with the same
// blockIdx%8, avoiding cross-XCD partial-line write amplification (round-4
// counter: scatb WRITE_SIZE=160MB for 12.8MB payload).
// Edge pass: one wave per dst, 16-edge chunks, wave-wide exp, unrolled PV gather.

#define NNODES 100000
#define NGRAPH 1024
#define NTYPES 4
#define NEDGES 800000
#define NEG_SLOPE 0.2f

#define TE (NTYPES * NEDGES)     // 3.2M edges
#define NRANGE 8                 // node ranges (XCD-ownership heuristic)
#define RSPAN 12500              // nodes per range
#define RCB 128                  // blocks per range

// ---------------- CSR pass 1: range-partitioned per-node count ----------------
__global__ __launch_bounds__(256) void rc_count(const int* __restrict__ dst,
                                                int* __restrict__ cnt) {
    int r = blockIdx.x & 7;          // range == XCD (heuristic: bid%8)
    int m = blockIdx.x >> 3;         // slice index in [0, RCB)
    for (int i = m * 256 + threadIdx.x; i < TE; i += RCB * 256) {
        int d = dst[i];
        if (d / RSPAN == r) {
            int t = i / NEDGES;
            atomicAdd(&cnt[t * NNODES + d], 1);
        }
    }
}

// ---------------- scan over T*N counts (1024 per block) ----------------
__global__ void scan1_kernel(const int* __restrict__ cnt, int* __restrict__ offs,
                             int* __restrict__ bsum) {
    __shared__ int sh[256];
    const int M = NTYPES * NNODES;
    int base = blockIdx.x * 1024 + threadIdx.x * 4;
    int v[4]; int tot = 0;
#pragma unroll
    for (int j = 0; j < 4; j++) {
        int idx = base + j;
        v[j] = (idx < M) ? cnt[idx] : 0;
        tot += v[j];
    }
    sh[threadIdx.x] = tot;
    __syncthreads();
    for (int off = 1; off < 256; off <<= 1) {
        int add = (threadIdx.x >= off) ? sh[threadIdx.x - off] : 0;
        __syncthreads();
        sh[threadIdx.x] += add;
        __syncthreads();
    }
    int excl = sh[threadIdx.x] - tot;
#pragma unroll
    for (int j = 0; j < 4; j++) {
        int idx = base + j;
        if (idx < M) offs[idx] = excl;
        excl += v[j];
    }
    if (threadIdx.x == 255) bsum[blockIdx.x] = sh[255];
}

__global__ void scan2_kernel(int* __restrict__ bsum, int nb) {
    __shared__ int sh[512];
    int v = (threadIdx.x < nb) ? bsum[threadIdx.x] : 0;
    sh[threadIdx.x] = v;
    __syncthreads();
    for (int off = 1; off < 512; off <<= 1) {
        int add = (threadIdx.x >= off) ? sh[threadIdx.x - off] : 0;
        __syncthreads();
        sh[threadIdx.x] += add;
        __syncthreads();
    }
    if (threadIdx.x < nb) bsum[threadIdx.x] = sh[threadIdx.x] - v;  // exclusive
}

__global__ void scan3_kernel(int* __restrict__ offs, const int* __restrict__ bsum) {
    const int M = NTYPES * NNODES;
    int i = blockIdx.x * 256 + threadIdx.x;
    if (i < M) offs[i] += bsum[i >> 10];
    if (i == 0) offs[M] = TE;  // sentinel
}

// ---------------- CSR pass 2: range-partitioned fill ----------------
__global__ __launch_bounds__(256) void rc_fill(const int* __restrict__ dst,
                                               const int* __restrict__ src,
                                               const int* __restrict__ offs,
                                               int* __restrict__ fillpos,
                                               int* __restrict__ csr) {
    int r = blockIdx.x & 7;
    int m = blockIdx.x >> 3;
    for (int i = m * 256 + threadIdx.x; i < TE; i += RCB * 256) {
        int d = dst[i];
        if (d / RSPAN == r) {
            int t = i / NEDGES;
            int idx = t * NNODES + d;
            int pos = atomicAdd(&fillpos[idx], 1);
            csr[offs[idx] + pos] = src[i];
        }
    }
}

// ---------------- embedding gather (layer-0 input) ----------------
__global__ void gather_kernel(const int* __restrict__ ids, const float* __restrict__ table,
                              float* __restrict__ h0) {
    int i = blockIdx.x * 256 + threadIdx.x;
    if (i < NNODES * 32) {
        int n = i >> 5, k = i & 31;
        h0[i] = table[ids[n] * 32 + k];
    }
}

// ---------------- feat = h @ W_t, plus el/er attention dots ----------------
template <int K>
__global__ __launch_bounds__(256) void feat_kernel(
    const float* __restrict__ h, const float* __restrict__ W,
    const float* __restrict__ al, const float* __restrict__ ar,
    float* __restrict__ feat, float* __restrict__ el, float* __restrict__ er) {
    int lane = threadIdx.x & 63;
    int wid = blockIdx.x * (blockDim.x >> 6) + (threadIdx.x >> 6);
    int nw = gridDim.x * (blockDim.x >> 6);
    float Wc[K];
#pragma unroll
    for (int k = 0; k < K; k++) Wc[k] = W[k * 64 + lane];
    float alr = al[lane];
    float arr = ar[lane];
    for (int n = wid; n < NNODES; n += nw) {
        const float* hp = h + n * K;
        float acc = 0.f;
#pragma unroll
        for (int k4 = 0; k4 < K; k4 += 4) {
            float4 hv = *reinterpret_cast<const float4*>(hp + k4);
            acc = fmaf(hv.x, Wc[k4 + 0], acc);
            acc = fmaf(hv.y, Wc[k4 + 1], acc);
            acc = fmaf(hv.z, Wc[k4 + 2], acc);
            acc = fmaf(hv.w, Wc[k4 + 3], acc);
        }
        feat[n * 64 + lane] = acc;
        float p = acc * alr, q = acc * arr;
#pragma unroll
        for (int s = 1; s < 16; s <<= 1) {
            p += __shfl_xor(p, s, 64);
            q += __shfl_xor(q, s, 64);
        }
        if ((lane & 15) == 0) {
            el[n * 4 + (lane >> 4)] = p;
            er[n * 4 + (lane >> 4)] = q;
        }
    }
}

// ---------------- edge pass: one wave per dst, 16-edge chunks ----------------
// Phase 1 layout: lane = 4*edge_slot + head  (16 edges x 4 heads)
// Phase 2 layout: lane = channel c, head = c>>4
template <bool FIRST, bool RELU>
__global__ __launch_bounds__(256) void edge_kernel(
    const int* __restrict__ csr, const int* __restrict__ offs,  // offs already + t*N
    const float* __restrict__ el, const float* __restrict__ er,
    const float* __restrict__ feat, const float* __restrict__ b,
    float* __restrict__ hnext) {
    int lane = threadIdx.x & 63;
    int d = blockIdx.x * 4 + (threadIdx.x >> 6);
    if (d >= NNODES) return;
    int hp = lane & 3;   // phase-1 head
    int h2 = lane >> 4;  // phase-2 head
    int j = lane >> 2;   // phase-1 edge slot
    int o0 = offs[d], o1 = offs[d + 1];
    float erv = er[d * 4 + hp];
    float m = -INFINITY, z = 0.f, acc = 0.f;
    for (int base = o0; base < o1; base += 16) {
        int cnt = o1 - base; if (cnt > 16) cnt = 16;
        int idx = base + j; if (idx > o1 - 1) idx = o1 - 1;  // clamp in-bounds
        int s = csr[idx];                    // coalesced 64B read
        bool valid = j < cnt;
        float e = el[s * 4 + hp] + erv;      // 16-line gather
        e = e > 0.f ? e : NEG_SLOPE * e;
        if (!valid) e = -INFINITY;
        float cm = e;                        // per-head chunk max (reduce over edge slots)
        cm = fmaxf(cm, __shfl_xor(cm, 4));
        cm = fmaxf(cm, __shfl_xor(cm, 8));
        cm = fmaxf(cm, __shfl_xor(cm, 16));
        cm = fmaxf(cm, __shfl_xor(cm, 32));
        float mn = fmaxf(m, cm);
        float corr = __expf(m - mn);         // first chunk: exp(-inf)=0
        float p = valid ? __expf(e - mn) : 0.f;  // one wave-wide exp for 64 (edge,head)
        float zc = p;
        zc += __shfl_xor(zc, 4);
        zc += __shfl_xor(zc, 8);
        zc += __shfl_xor(zc, 16);
        zc += __shfl_xor(zc, 32);
        z = z * corr + zc;
        float corr2 = __shfl(corr, h2);      // corr for this channel's head
        acc *= corr2;
#pragma unroll
        for (int k = 0; k < 16; k++) {       // PV: 16 independent feat gathers
            int kk = (k < cnt) ? k : 0;      // clamped slots hit slot-0's lines (L1)
            int sk = __shfl(s, kk << 2);
            float pk = __shfl(p, (kk << 2) | h2);
            if (k >= cnt) pk = 0.f;
            acc = fmaf(pk, feat[sk * 64 + lane], acc);
        }
        m = mn;
    }
    float z2 = __shfl(z, h2);
    float val = (o1 > o0) ? acc / z2 : 0.f;
    val += b[lane];
    float out = FIRST ? val : hnext[d * 64 + lane] + val;
    if (RELU) out = fmaxf(out, 0.f);
    hnext[d * 64 + lane] = out;
}

// ---------------- readout ----------------
__global__ void embed_kernel(const int* __restrict__ gid, const float* __restrict__ h,
                             float* __restrict__ out) {
    int bg = blockIdx.x;
    int lane = threadIdx.x;
    int lo = 0, hi = NNODES;
    while (lo < hi) { int mid = (lo + hi) >> 1; if (gid[mid] < bg) lo = mid + 1; else hi = mid; }
    int start = lo;
    hi = NNODES;
    while (lo < hi) { int mid = (lo + hi) >> 1; if (gid[mid] < bg + 1) lo = mid + 1; else hi = mid; }
    int end = lo;
    float s = 0.f;
    for (int n = start; n < end; n++) s += h[n * 64 + lane];
    out[bg * 64 + lane] = s;
}

__global__ void score_kernel(const float* __restrict__ ow1, const float* __restrict__ ob1,
                             const float* __restrict__ ow2, const float* __restrict__ ob2,
                             const float* __restrict__ embed, float* __restrict__ score) {
    __shared__ float wc[64];
    __shared__ float cst;
    int tid = threadIdx.x;
    if (tid < 64) {
        float s = 0.f;
        for (int j = 0; j < 32; j++) s += ow1[tid * 32 + j] * ow2[j];
        wc[tid] = s;
    }
    if (tid == 64) {
        float s = 0.f;
        for (int j = 0; j < 32; j++) s += ob1[j] * ow2[j];
        cst = s + ob2[0];
    }
    __syncthreads();
    int bg = blockIdx.x * blockDim.x + tid;
    if (bg < NGRAPH) {
        float s = cst;
        for (int c = 0; c < 64; c++) s = fmaf(embed[bg * 64 + c], wc[c], s);
        score[bg] = s;
    }
}

extern "C" void kernel_launch(void* const* d_in, const int* in_sizes, int n_in,
                              void* d_out, int out_size, void* d_ws, size_t ws_size,
                              hipStream_t stream) {
    const int* node_ids  = (const int*)d_in[0];
    const int* graph_ids = (const int*)d_in[1];
    const int* src       = (const int*)d_in[2];
    const int* dst       = (const int*)d_in[3];
    const float* table   = (const float*)d_in[4];
    const float* Wm[3]  = {(const float*)d_in[5],  (const float*)d_in[9],  (const float*)d_in[13]};
    const float* alm[3] = {(const float*)d_in[6],  (const float*)d_in[10], (const float*)d_in[14]};
    const float* arm[3] = {(const float*)d_in[7],  (const float*)d_in[11], (const float*)d_in[15]};
    const float* bm[3]  = {(const float*)d_in[8],  (const float*)d_in[12], (const float*)d_in[16]};
    const float* ow1 = (const float*)d_in[17];
    const float* ob1 = (const float*)d_in[18];
    const float* ow2 = (const float*)d_in[19];
    const float* ob2 = (const float*)d_in[20];

    float* out_embed = (float*)d_out;
    float* out_score = out_embed + NGRAPH * 64;

    // ---- workspace layout ----
    char* w = (char*)d_ws;
    float* hA = (float*)w;    w += 4ull * NNODES * 64;          // 25.6MB
    float* hB = (float*)w;    w += 4ull * NNODES * 64;          // 25.6MB
    float* feat = (float*)w;  w += 4ull * NNODES * 64;          // 25.6MB
    int* csr = (int*)w;       w += 4ull * TE;                   // 12.8MB
    int* offs = (int*)w;      w += 4ull * (NTYPES * NNODES + 16);
    float* elb = (float*)w;   w += 4ull * NNODES * 4;
    float* erb = (float*)w;   w += 4ull * NNODES * 4;
    int* cnt = (int*)w;       w += 4ull * NTYPES * NNODES;      // 1.6MB
    int* fillpos = (int*)w;   w += 4ull * NTYPES * NNODES;      // 1.6MB
    int* bsum = (int*)w;      w += 4ull * 512;

    const int M = NTYPES * NNODES;
    const int NB = (M + 1023) / 1024;  // 391 (<=512 for scan2)

    // ---- CSR build (range-partitioned, write-amp-free) ----
    hipMemsetAsync(cnt, 0, sizeof(int) * M, stream);
    hipMemsetAsync(fillpos, 0, sizeof(int) * M, stream);
    rc_count<<<NRANGE * RCB, 256, 0, stream>>>(dst, cnt);
    scan1_kernel<<<NB, 256, 0, stream>>>(cnt, offs, bsum);
    scan2_kernel<<<1, 512, 0, stream>>>(bsum, NB);
    scan3_kernel<<<(M + 255) / 256, 256, 0, stream>>>(offs, bsum);
    rc_fill<<<NRANGE * RCB, 256, 0, stream>>>(dst, src, offs, fillpos, csr);

    // ---- layer-0 input ----
    gather_kernel<<<(NNODES * 32 + 255) / 256, 256, 0, stream>>>(node_ids, table, hA);

    float* hin = hA;
    float* hout = hB;
    const int EDGE_GRID = (NNODES + 3) / 4;

    for (int L = 0; L < 3; L++) {
        for (int t = 0; t < NTYPES; t++) {
            const int K = (L == 0) ? 32 : 64;
            const float* Wt = Wm[L] + (size_t)t * K * 64;
            const float* alt = alm[L] + t * 64;
            const float* art = arm[L] + t * 64;
            const float* bt = bm[L] + t * 64;
            if (L == 0)
                feat_kernel<32><<<2048, 256, 0, stream>>>(hin, Wt, alt, art, feat, elb, erb);
            else
                feat_kernel<64><<<2048, 256, 0, stream>>>(hin, Wt, alt, art, feat, elb, erb);

            const int* offs_t = offs + t * NNODES;
            bool relu = (L < 2) && (t == NTYPES - 1);
            if (t == 0)
                edge_kernel<true, false><<<EDGE_GRID, 256, 0, stream>>>(csr, offs_t, elb, erb, feat, bt, hout);
            else if (relu)
                edge_kernel<false, true><<<EDGE_GRID, 256, 0, stream>>>(csr, offs_t, elb, erb, feat, bt, hout);
            else
                edge_kernel<false, false><<<EDGE_GRID, 256, 0, stream>>>(csr, offs_t, elb, erb, feat, bt, hout);
        }
        float* tmp = hin; hin = hout; hout = tmp;
    }

    embed_kernel<<<NGRAPH, 64, 0, stream>>>(graph_ids, hin, out_embed);
    score_kernel<<<(NGRAPH + 255) / 256, 256, 0, stream>>>(ow1, ob1, ow2, ob2, out_embed, out_score);
}

// Round 10
// 1620.535 us; speedup vs baseline: 1.0334x; 1.0334x over previous
//
#include <hip/hip_runtime.h>
#include <hip/hip_bf16.h>
#include <cstdint>

// HeteroGAT on MI355X.
// Round-9 change: fused 4-type edge kernel (one dispatch per layer, hnext
// written once, no RMW) behind a runtime ws_size check; fallback = round-8
// per-type path. CSR build / feat / readout unchanged.

#define NNODES 100000
#define NGRAPH 1024
#define NTYPES 4
#define NEDGES 800000
#define NEG_SLOPE 0.2f

#define TE (NTYPES * NEDGES)     // 3.2M edges
#define NRANGE 8                 // node ranges
#define RSPAN 12500              // nodes per range
#define RCB 128                  // blocks per range

// ---------------- CSR pass 1: range-partitioned per-node count ----------------
__global__ __launch_bounds__(256) void rc_count(const int* __restrict__ dst,
                                                int* __restrict__ cnt) {
    int r = blockIdx.x & 7;
    int m = blockIdx.x >> 3;
    for (int i = m * 256 + threadIdx.x; i < TE; i += RCB * 256) {
        int d = dst[i];
        if (d / RSPAN == r) {
            int t = i / NEDGES;
            atomicAdd(&cnt[t * NNODES + d], 1);
        }
    }
}

// ---------------- scan over T*N counts ----------------
__global__ void scan1_kernel(const int* __restrict__ cnt, int* __restrict__ offs,
                             int* __restrict__ bsum) {
    __shared__ int sh[256];
    const int M = NTYPES * NNODES;
    int base = blockIdx.x * 1024 + threadIdx.x * 4;
    int v[4]; int tot = 0;
#pragma unroll
    for (int j = 0; j < 4; j++) {
        int idx = base + j;
        v[j] = (idx < M) ? cnt[idx] : 0;
        tot += v[j];
    }
    sh[threadIdx.x] = tot;
    __syncthreads();
    for (int off = 1; off < 256; off <<= 1) {
        int add = (threadIdx.x >= off) ? sh[threadIdx.x - off] : 0;
        __syncthreads();
        sh[threadIdx.x] += add;
        __syncthreads();
    }
    int excl = sh[threadIdx.x] - tot;
#pragma unroll
    for (int j = 0; j < 4; j++) {
        int idx = base + j;
        if (idx < M) offs[idx] = excl;
        excl += v[j];
    }
    if (threadIdx.x == 255) bsum[blockIdx.x] = sh[255];
}

__global__ void scan2_kernel(int* __restrict__ bsum, int nb) {
    __shared__ int sh[512];
    int v = (threadIdx.x < nb) ? bsum[threadIdx.x] : 0;
    sh[threadIdx.x] = v;
    __syncthreads();
    for (int off = 1; off < 512; off <<= 1) {
        int add = (threadIdx.x >= off) ? sh[threadIdx.x - off] : 0;
        __syncthreads();
        sh[threadIdx.x] += add;
        __syncthreads();
    }
    if (threadIdx.x < nb) bsum[threadIdx.x] = sh[threadIdx.x] - v;
}

__global__ void scan3_kernel(int* __restrict__ offs, const int* __restrict__ bsum) {
    const int M = NTYPES * NNODES;
    int i = blockIdx.x * 256 + threadIdx.x;
    if (i < M) offs[i] += bsum[i >> 10];
    if (i == 0) offs[M] = TE;
}

// ---------------- CSR pass 2: range-partitioned fill ----------------
__global__ __launch_bounds__(256) void rc_fill(const int* __restrict__ dst,
                                               const int* __restrict__ src,
                                               const int* __restrict__ offs,
                                               int* __restrict__ fillpos,
                                               int* __restrict__ csr) {
    int r = blockIdx.x & 7;
    int m = blockIdx.x >> 3;
    for (int i = m * 256 + threadIdx.x; i < TE; i += RCB * 256) {
        int d = dst[i];
        if (d / RSPAN == r) {
            int t = i / NEDGES;
            int idx = t * NNODES + d;
            int pos = atomicAdd(&fillpos[idx], 1);
            csr[offs[idx] + pos] = src[i];
        }
    }
}

// ---------------- embedding gather ----------------
__global__ void gather_kernel(const int* __restrict__ ids, const float* __restrict__ table,
                              float* __restrict__ h0) {
    int i = blockIdx.x * 256 + threadIdx.x;
    if (i < NNODES * 32) {
        int n = i >> 5, k = i & 31;
        h0[i] = table[ids[n] * 32 + k];
    }
}

// ---------------- feat = h @ W_t, plus el/er attention dots ----------------
template <int K>
__global__ __launch_bounds__(256) void feat_kernel(
    const float* __restrict__ h, const float* __restrict__ W,
    const float* __restrict__ al, const float* __restrict__ ar,
    float* __restrict__ feat, float* __restrict__ el, float* __restrict__ er) {
    int lane = threadIdx.x & 63;
    int wid = blockIdx.x * (blockDim.x >> 6) + (threadIdx.x >> 6);
    int nw = gridDim.x * (blockDim.x >> 6);
    float Wc[K];
#pragma unroll
    for (int k = 0; k < K; k++) Wc[k] = W[k * 64 + lane];
    float alr = al[lane];
    float arr = ar[lane];
    for (int n = wid; n < NNODES; n += nw) {
        const float* hp = h + n * K;
        float acc = 0.f;
#pragma unroll
        for (int k4 = 0; k4 < K; k4 += 4) {
            float4 hv = *reinterpret_cast<const float4*>(hp + k4);
            acc = fmaf(hv.x, Wc[k4 + 0], acc);
            acc = fmaf(hv.y, Wc[k4 + 1], acc);
            acc = fmaf(hv.z, Wc[k4 + 2], acc);
            acc = fmaf(hv.w, Wc[k4 + 3], acc);
        }
        feat[n * 64 + lane] = acc;
        float p = acc * alr, q = acc * arr;
#pragma unroll
        for (int s = 1; s < 16; s <<= 1) {
            p += __shfl_xor(p, s, 64);
            q += __shfl_xor(q, s, 64);
        }
        if ((lane & 15) == 0) {
            el[n * 4 + (lane >> 4)] = p;
            er[n * 4 + (lane >> 4)] = q;
        }
    }
}

// ---------------- fused edge pass: all 4 types, one wave per dst ----------------
// Per type: 16-edge chunks, wave-wide exp, unrolled PV gather; out summed in regs.
template <bool RELU>
__global__ __launch_bounds__(256) void edge4_kernel(
    const int* __restrict__ csr, const int* __restrict__ offs,   // [4N+1]
    const float* __restrict__ el4, const float* __restrict__ er4, // [4][N][4]
    const float* __restrict__ feat4,                              // [4][N][64]
    const float* __restrict__ b,                                  // [4][64]
    float* __restrict__ hnext) {
    int lane = threadIdx.x & 63;
    int d = blockIdx.x * 4 + (threadIdx.x >> 6);
    if (d >= NNODES) return;
    int hp = lane & 3;   // phase-1 head
    int h2 = lane >> 4;  // phase-2 head
    int j = lane >> 2;   // phase-1 edge slot
    float out = 0.f;
    for (int t = 0; t < NTYPES; t++) {
        int nd = t * NNODES + d;
        int o0 = offs[nd], o1 = offs[nd + 1];
        const float* el = el4 + (size_t)t * NNODES * 4;
        const float* feat = feat4 + (size_t)t * NNODES * 64;
        float erv = er4[(size_t)nd * 4 + hp];
        float m = -INFINITY, z = 0.f, acc = 0.f;
        for (int base = o0; base < o1; base += 16) {
            int cnt = o1 - base; if (cnt > 16) cnt = 16;
            int idx = base + j; if (idx > o1 - 1) idx = o1 - 1;
            int s = csr[idx];
            bool valid = j < cnt;
            float e = el[s * 4 + hp] + erv;
            e = e > 0.f ? e : NEG_SLOPE * e;
            if (!valid) e = -INFINITY;
            float cm = e;
            cm = fmaxf(cm, __shfl_xor(cm, 4));
            cm = fmaxf(cm, __shfl_xor(cm, 8));
            cm = fmaxf(cm, __shfl_xor(cm, 16));
            cm = fmaxf(cm, __shfl_xor(cm, 32));
            float mn = fmaxf(m, cm);
            float corr = __expf(m - mn);
            float p = valid ? __expf(e - mn) : 0.f;
            float zc = p;
            zc += __shfl_xor(zc, 4);
            zc += __shfl_xor(zc, 8);
            zc += __shfl_xor(zc, 16);
            zc += __shfl_xor(zc, 32);
            z = z * corr + zc;
            float corr2 = __shfl(corr, h2);
            acc *= corr2;
#pragma unroll
            for (int k = 0; k < 16; k++) {
                int kk = (k < cnt) ? k : 0;
                int sk = __shfl(s, kk << 2);
                float pk = __shfl(p, (kk << 2) | h2);
                if (k >= cnt) pk = 0.f;
                acc = fmaf(pk, feat[sk * 64 + lane], acc);
            }
            m = mn;
        }
        float z2 = __shfl(z, h2);
        float val = (o1 > o0) ? acc / z2 : 0.f;
        out += val + b[t * 64 + lane];
    }
    if (RELU) out = fmaxf(out, 0.f);
    hnext[d * 64 + lane] = out;
}

// ---------------- per-type edge pass (fallback, round-8) ----------------
template <bool FIRST, bool RELU>
__global__ __launch_bounds__(256) void edge_kernel(
    const int* __restrict__ csr, const int* __restrict__ offs,
    const float* __restrict__ el, const float* __restrict__ er,
    const float* __restrict__ feat, const float* __restrict__ b,
    float* __restrict__ hnext) {
    int lane = threadIdx.x & 63;
    int d = blockIdx.x * 4 + (threadIdx.x >> 6);
    if (d >= NNODES) return;
    int hp = lane & 3;
    int h2 = lane >> 4;
    int j = lane >> 2;
    int o0 = offs[d], o1 = offs[d + 1];
    float erv = er[d * 4 + hp];
    float m = -INFINITY, z = 0.f, acc = 0.f;
    for (int base = o0; base < o1; base += 16) {
        int cnt = o1 - base; if (cnt > 16) cnt = 16;
        int idx = base + j; if (idx > o1 - 1) idx = o1 - 1;
        int s = csr[idx];
        bool valid = j < cnt;
        float e = el[s * 4 + hp] + erv;
        e = e > 0.f ? e : NEG_SLOPE * e;
        if (!valid) e = -INFINITY;
        float cm = e;
        cm = fmaxf(cm, __shfl_xor(cm, 4));
        cm = fmaxf(cm, __shfl_xor(cm, 8));
        cm = fmaxf(cm, __shfl_xor(cm, 16));
        cm = fmaxf(cm, __shfl_xor(cm, 32));
        float mn = fmaxf(m, cm);
        float corr = __expf(m - mn);
        float p = valid ? __expf(e - mn) : 0.f;
        float zc = p;
        zc += __shfl_xor(zc, 4);
        zc += __shfl_xor(zc, 8);
        zc += __shfl_xor(zc, 16);
        zc += __shfl_xor(zc, 32);
        z = z * corr + zc;
        float corr2 = __shfl(corr, h2);
        acc *= corr2;
#pragma unroll
        for (int k = 0; k < 16; k++) {
            int kk = (k < cnt) ? k : 0;
            int sk = __shfl(s, kk << 2);
            float pk = __shfl(p, (kk << 2) | h2);
            if (k >= cnt) pk = 0.f;
            acc = fmaf(pk, feat[sk * 64 + lane], acc);
        }
        m = mn;
    }
    float z2 = __shfl(z, h2);
    float val = (o1 > o0) ? acc / z2 : 0.f;
    val += b[lane];
    float out = FIRST ? val : hnext[d * 64 + lane] + val;
    if (RELU) out = fmaxf(out, 0.f);
    hnext[d * 64 + lane] = out;
}

// ---------------- readout ----------------
__global__ void embed_kernel(const int* __restrict__ gid, const float* __restrict__ h,
                             float* __restrict__ out) {
    int bg = blockIdx.x;
    int lane = threadIdx.x;
    int lo = 0, hi = NNODES;
    while (lo < hi) { int mid = (lo + hi) >> 1; if (gid[mid] < bg) lo = mid + 1; else hi = mid; }
    int start = lo;
    hi = NNODES;
    while (lo < hi) { int mid = (lo + hi) >> 1; if (gid[mid] < bg + 1) lo = mid + 1; else hi = mid; }
    int end = lo;
    float s = 0.f;
    for (int n = start; n < end; n++) s += h[n * 64 + lane];
    out[bg * 64 + lane] = s;
}

__global__ void score_kernel(const float* __restrict__ ow1, const float* __restrict__ ob1,
                             const float* __restrict__ ow2, const float* __restrict__ ob2,
                             const float* __restrict__ embed, float* __restrict__ score) {
    __shared__ float wc[64];
    __shared__ float cst;
    int tid = threadIdx.x;
    if (tid < 64) {
        float s = 0.f;
        for (int j = 0; j < 32; j++) s += ow1[tid * 32 + j] * ow2[j];
        wc[tid] = s;
    }
    if (tid == 64) {
        float s = 0.f;
        for (int j = 0; j < 32; j++) s += ob1[j] * ow2[j];
        cst = s + ob2[0];
    }
    __syncthreads();
    int bg = blockIdx.x * blockDim.x + tid;
    if (bg < NGRAPH) {
        float s = cst;
        for (int c = 0; c < 64; c++) s = fmaf(embed[bg * 64 + c], wc[c], s);
        score[bg] = s;
    }
}

extern "C" void kernel_launch(void* const* d_in, const int* in_sizes, int n_in,
                              void* d_out, int out_size, void* d_ws, size_t ws_size,
                              hipStream_t stream) {
    const int* node_ids  = (const int*)d_in[0];
    const int* graph_ids = (const int*)d_in[1];
    const int* src       = (const int*)d_in[2];
    const int* dst       = (const int*)d_in[3];
    const float* table   = (const float*)d_in[4];
    const float* Wm[3]  = {(const float*)d_in[5],  (const float*)d_in[9],  (const float*)d_in[13]};
    const float* alm[3] = {(const float*)d_in[6],  (const float*)d_in[10], (const float*)d_in[14]};
    const float* arm[3] = {(const float*)d_in[7],  (const float*)d_in[11], (const float*)d_in[15]};
    const float* bm[3]  = {(const float*)d_in[8],  (const float*)d_in[12], (const float*)d_in[16]};
    const float* ow1 = (const float*)d_in[17];
    const float* ob1 = (const float*)d_in[18];
    const float* ow2 = (const float*)d_in[19];
    const float* ob2 = (const float*)d_in[20];

    float* out_embed = (float*)d_out;
    float* out_score = out_embed + NGRAPH * 64;

    const int M = NTYPES * NNODES;
    const int NB = (M + 1023) / 1024;
    const int EDGE_GRID = (NNODES + 3) / 4;

    // fused layout size: h + feat4 + csr + offs + el4 + er4 + cnt + fillpos + bsum
    const size_t NEED_FUSED =
        4ull * NNODES * 64 +            // h (in-place)
        4ull * NTYPES * NNODES * 64 +   // feat4
        4ull * TE +                     // csr
        4ull * (M + 16) +               // offs
        4ull * NTYPES * NNODES * 4 +    // el4
        4ull * NTYPES * NNODES * 4 +    // er4
        4ull * M +                      // cnt
        4ull * M +                      // fillpos
        4096;                           // bsum

    if (ws_size >= NEED_FUSED) {
        // ---- fused path ----
        char* w = (char*)d_ws;
        float* h = (float*)w;      w += 4ull * NNODES * 64;
        float* feat4 = (float*)w;  w += 4ull * NTYPES * NNODES * 64;
        int* csr = (int*)w;        w += 4ull * TE;
        int* offs = (int*)w;       w += 4ull * (M + 16);
        float* el4 = (float*)w;    w += 4ull * NTYPES * NNODES * 4;
        float* er4 = (float*)w;    w += 4ull * NTYPES * NNODES * 4;
        int* cnt = (int*)w;        w += 4ull * M;
        int* fillpos = (int*)w;    w += 4ull * M;
        int* bsum = (int*)w;       w += 4096;

        hipMemsetAsync(cnt, 0, sizeof(int) * M, stream);
        hipMemsetAsync(fillpos, 0, sizeof(int) * M, stream);
        rc_count<<<NRANGE * RCB, 256, 0, stream>>>(dst, cnt);
        scan1_kernel<<<NB, 256, 0, stream>>>(cnt, offs, bsum);
        scan2_kernel<<<1, 512, 0, stream>>>(bsum, NB);
        scan3_kernel<<<(M + 255) / 256, 256, 0, stream>>>(offs, bsum);
        rc_fill<<<NRANGE * RCB, 256, 0, stream>>>(dst, src, offs, fillpos, csr);

        gather_kernel<<<(NNODES * 32 + 255) / 256, 256, 0, stream>>>(node_ids, table, h);

        for (int L = 0; L < 3; L++) {
            const int K = (L == 0) ? 32 : 64;
            for (int t = 0; t < NTYPES; t++) {
                const float* Wt = Wm[L] + (size_t)t * K * 64;
                float* ft = feat4 + (size_t)t * NNODES * 64;
                float* elt = el4 + (size_t)t * NNODES * 4;
                float* ert = er4 + (size_t)t * NNODES * 4;
                if (L == 0)
                    feat_kernel<32><<<2048, 256, 0, stream>>>(h, Wt, alm[L] + t * 64, arm[L] + t * 64, ft, elt, ert);
                else
                    feat_kernel<64><<<2048, 256, 0, stream>>>(h, Wt, alm[L] + t * 64, arm[L] + t * 64, ft, elt, ert);
            }
            if (L < 2)
                edge4_kernel<true><<<EDGE_GRID, 256, 0, stream>>>(csr, offs, el4, er4, feat4, bm[L], h);
            else
                edge4_kernel<false><<<EDGE_GRID, 256, 0, stream>>>(csr, offs, el4, er4, feat4, bm[L], h);
        }

        embed_kernel<<<NGRAPH, 64, 0, stream>>>(graph_ids, h, out_embed);
        score_kernel<<<(NGRAPH + 255) / 256, 256, 0, stream>>>(ow1, ob1, ow2, ob2, out_embed, out_score);
    } else {
        // ---- fallback: round-8 per-type path ----
        char* w = (char*)d_ws;
        float* hA = (float*)w;    w += 4ull * NNODES * 64;
        float* hB = (float*)w;    w += 4ull * NNODES * 64;
        float* feat = (float*)w;  w += 4ull * NNODES * 64;
        int* csr = (int*)w;       w += 4ull * TE;
        int* offs = (int*)w;      w += 4ull * (M + 16);
        float* elb = (float*)w;   w += 4ull * NNODES * 4;
        float* erb = (float*)w;   w += 4ull * NNODES * 4;
        int* cnt = (int*)w;       w += 4ull * M;
        int* fillpos = (int*)w;   w += 4ull * M;
        int* bsum = (int*)w;      w += 4096;

        hipMemsetAsync(cnt, 0, sizeof(int) * M, stream);
        hipMemsetAsync(fillpos, 0, sizeof(int) * M, stream);
        rc_count<<<NRANGE * RCB, 256, 0, stream>>>(dst, cnt);
        scan1_kernel<<<NB, 256, 0, stream>>>(cnt, offs, bsum);
        scan2_kernel<<<1, 512, 0, stream>>>(bsum, NB);
        scan3_kernel<<<(M + 255) / 256, 256, 0, stream>>>(offs, bsum);
        rc_fill<<<NRANGE * RCB, 256, 0, stream>>>(dst, src, offs, fillpos, csr);

        gather_kernel<<<(NNODES * 32 + 255) / 256, 256, 0, stream>>>(node_ids, table, hA);

        float* hin = hA;
        float* hout = hB;
        for (int L = 0; L < 3; L++) {
            for (int t = 0; t < NTYPES; t++) {
                const int K = (L == 0) ? 32 : 64;
                const float* Wt = Wm[L] + (size_t)t * K * 64;
                if (L == 0)
                    feat_kernel<32><<<2048, 256, 0, stream>>>(hin, Wt, alm[L] + t * 64, arm[L] + t * 64, feat, elb, erb);
                else
                    feat_kernel<64><<<2048, 256, 0, stream>>>(hin, Wt, alm[L] + t * 64, arm[L] + t * 64, feat, elb, erb);

                const int* offs_t = offs + t * NNODES;
                bool relu = (L < 2) && (t == NTYPES - 1);
                if (t == 0)
                    edge_kernel<true, false><<<EDGE_GRID, 256, 0, stream>>>(csr, offs_t, elb, erb, feat, bm[L] + t * 64, hout);
                else if (relu)
                    edge_kernel<false, true><<<EDGE_GRID, 256, 0, stream>>>(csr, offs_t, elb, erb, feat, bm[L] + t * 64, hout);
                else
                    edge_kernel<false, false><<<EDGE_GRID, 256, 0, stream>>>(csr, offs_t, elb, erb, feat, bm[L] + t * 64, hout);
            }
            float* tmp = hin; hin = hout; hout = tmp;
        }

        embed_kernel<<<NGRAPH, 64, 0, stream>>>(graph_ids, hin, out_embed);
        score_kernel<<<(NGRAPH + 255) / 256, 256, 0, stream>>>(ow1, ob1, ow2, ob2, out_embed, out_score);
    }
}

// Round 11
// 1572.104 us; speedup vs baseline: 1.0652x; 1.0308x over previous
//
#include <hip/hip_runtime.h>
#include <hip/hip_bf16.h>
#include <cstdint>

// HeteroGAT on MI355X.
// Round-11: edge4 PV via per-wave LDS staging + runtime-bounded (ceil4) loop
// (mean degree 8 -> halves PV iterations vs fixed-16 unroll; removes bpermute
// broadcasts); feat kernel processes 4 nodes per wave for 4-way ILP on the
// dependent fma chains. Fallback path removed (round-10 ran fused: ws >= 158MB).

#define NNODES 100000
#define NGRAPH 1024
#define NTYPES 4
#define NEDGES 800000
#define NEG_SLOPE 0.2f

#define TE (NTYPES * NEDGES)     // 3.2M edges
#define NRANGE 8
#define RSPAN 12500
#define RCB 128

// ---------------- CSR pass 1: range-partitioned per-node count ----------------
__global__ __launch_bounds__(256) void rc_count(const int* __restrict__ dst,
                                                int* __restrict__ cnt) {
    int r = blockIdx.x & 7;
    int m = blockIdx.x >> 3;
    for (int i = m * 256 + threadIdx.x; i < TE; i += RCB * 256) {
        int d = dst[i];
        if (d / RSPAN == r) {
            int t = i / NEDGES;
            atomicAdd(&cnt[t * NNODES + d], 1);
        }
    }
}

// ---------------- scan over T*N counts ----------------
__global__ void scan1_kernel(const int* __restrict__ cnt, int* __restrict__ offs,
                             int* __restrict__ bsum) {
    __shared__ int sh[256];
    const int M = NTYPES * NNODES;
    int base = blockIdx.x * 1024 + threadIdx.x * 4;
    int v[4]; int tot = 0;
#pragma unroll
    for (int j = 0; j < 4; j++) {
        int idx = base + j;
        v[j] = (idx < M) ? cnt[idx] : 0;
        tot += v[j];
    }
    sh[threadIdx.x] = tot;
    __syncthreads();
    for (int off = 1; off < 256; off <<= 1) {
        int add = (threadIdx.x >= off) ? sh[threadIdx.x - off] : 0;
        __syncthreads();
        sh[threadIdx.x] += add;
        __syncthreads();
    }
    int excl = sh[threadIdx.x] - tot;
#pragma unroll
    for (int j = 0; j < 4; j++) {
        int idx = base + j;
        if (idx < M) offs[idx] = excl;
        excl += v[j];
    }
    if (threadIdx.x == 255) bsum[blockIdx.x] = sh[255];
}

__global__ void scan2_kernel(int* __restrict__ bsum, int nb) {
    __shared__ int sh[512];
    int v = (threadIdx.x < nb) ? bsum[threadIdx.x] : 0;
    sh[threadIdx.x] = v;
    __syncthreads();
    for (int off = 1; off < 512; off <<= 1) {
        int add = (threadIdx.x >= off) ? sh[threadIdx.x - off] : 0;
        __syncthreads();
        sh[threadIdx.x] += add;
        __syncthreads();
    }
    if (threadIdx.x < nb) bsum[threadIdx.x] = sh[threadIdx.x] - v;
}

__global__ void scan3_kernel(int* __restrict__ offs, const int* __restrict__ bsum) {
    const int M = NTYPES * NNODES;
    int i = blockIdx.x * 256 + threadIdx.x;
    if (i < M) offs[i] += bsum[i >> 10];
    if (i == 0) offs[M] = TE;
}

// ---------------- CSR pass 2: range-partitioned fill ----------------
__global__ __launch_bounds__(256) void rc_fill(const int* __restrict__ dst,
                                               const int* __restrict__ src,
                                               const int* __restrict__ offs,
                                               int* __restrict__ fillpos,
                                               int* __restrict__ csr) {
    int r = blockIdx.x & 7;
    int m = blockIdx.x >> 3;
    for (int i = m * 256 + threadIdx.x; i < TE; i += RCB * 256) {
        int d = dst[i];
        if (d / RSPAN == r) {
            int t = i / NEDGES;
            int idx = t * NNODES + d;
            int pos = atomicAdd(&fillpos[idx], 1);
            csr[offs[idx] + pos] = src[i];
        }
    }
}

// ---------------- embedding gather ----------------
__global__ void gather_kernel(const int* __restrict__ ids, const float* __restrict__ table,
                              float* __restrict__ h0) {
    int i = blockIdx.x * 256 + threadIdx.x;
    if (i < NNODES * 32) {
        int n = i >> 5, k = i & 31;
        h0[i] = table[ids[n] * 32 + k];
    }
}

// ---------------- feat = h @ W_t + attention dots; 4 nodes/wave for ILP ------
template <int K>
__global__ __launch_bounds__(256) void feat_kernel(
    const float* __restrict__ h, const float* __restrict__ W,
    const float* __restrict__ al, const float* __restrict__ ar,
    float* __restrict__ feat, float* __restrict__ el, float* __restrict__ er) {
    int lane = threadIdx.x & 63;
    int wid = blockIdx.x * (blockDim.x >> 6) + (threadIdx.x >> 6);
    int nw = gridDim.x * (blockDim.x >> 6);
    float Wc[K];
#pragma unroll
    for (int k = 0; k < K; k++) Wc[k] = W[k * 64 + lane];
    float alr = al[lane];
    float arr = ar[lane];
    for (int n4 = wid * 4; n4 < NNODES; n4 += nw * 4) {
        const float* hp0 = h + (size_t)n4 * K;
        float a0 = 0.f, a1 = 0.f, a2 = 0.f, a3 = 0.f;
#pragma unroll
        for (int k4 = 0; k4 < K; k4 += 4) {
            float4 v0 = *reinterpret_cast<const float4*>(hp0 + k4);
            float4 v1 = *reinterpret_cast<const float4*>(hp0 + K + k4);
            float4 v2 = *reinterpret_cast<const float4*>(hp0 + 2 * K + k4);
            float4 v3 = *reinterpret_cast<const float4*>(hp0 + 3 * K + k4);
            a0 = fmaf(v0.x, Wc[k4 + 0], a0); a0 = fmaf(v0.y, Wc[k4 + 1], a0);
            a0 = fmaf(v0.z, Wc[k4 + 2], a0); a0 = fmaf(v0.w, Wc[k4 + 3], a0);
            a1 = fmaf(v1.x, Wc[k4 + 0], a1); a1 = fmaf(v1.y, Wc[k4 + 1], a1);
            a1 = fmaf(v1.z, Wc[k4 + 2], a1); a1 = fmaf(v1.w, Wc[k4 + 3], a1);
            a2 = fmaf(v2.x, Wc[k4 + 0], a2); a2 = fmaf(v2.y, Wc[k4 + 1], a2);
            a2 = fmaf(v2.z, Wc[k4 + 2], a2); a2 = fmaf(v2.w, Wc[k4 + 3], a2);
            a3 = fmaf(v3.x, Wc[k4 + 0], a3); a3 = fmaf(v3.y, Wc[k4 + 1], a3);
            a3 = fmaf(v3.z, Wc[k4 + 2], a3); a3 = fmaf(v3.w, Wc[k4 + 3], a3);
        }
        feat[(size_t)(n4 + 0) * 64 + lane] = a0;
        feat[(size_t)(n4 + 1) * 64 + lane] = a1;
        feat[(size_t)(n4 + 2) * 64 + lane] = a2;
        feat[(size_t)(n4 + 3) * 64 + lane] = a3;
        float p0 = a0 * alr, q0 = a0 * arr;
        float p1 = a1 * alr, q1 = a1 * arr;
        float p2 = a2 * alr, q2 = a2 * arr;
        float p3 = a3 * alr, q3 = a3 * arr;
#pragma unroll
        for (int s = 1; s < 16; s <<= 1) {
            p0 += __shfl_xor(p0, s, 64); q0 += __shfl_xor(q0, s, 64);
            p1 += __shfl_xor(p1, s, 64); q1 += __shfl_xor(q1, s, 64);
            p2 += __shfl_xor(p2, s, 64); q2 += __shfl_xor(q2, s, 64);
            p3 += __shfl_xor(p3, s, 64); q3 += __shfl_xor(q3, s, 64);
        }
        if ((lane & 15) == 0) {
            int hh = lane >> 4;
            el[(n4 + 0) * 4 + hh] = p0; er[(n4 + 0) * 4 + hh] = q0;
            el[(n4 + 1) * 4 + hh] = p1; er[(n4 + 1) * 4 + hh] = q1;
            el[(n4 + 2) * 4 + hh] = p2; er[(n4 + 2) * 4 + hh] = q2;
            el[(n4 + 3) * 4 + hh] = p3; er[(n4 + 3) * 4 + hh] = q3;
        }
    }
}

// ---------------- fused edge pass: all 4 types, one wave per dst --------------
// Softmax phase in lane layout (edge j = lane>>2, head hp = lane&3); PV phase
// reads (s,p) from per-wave LDS staging with a runtime-bounded ceil4 loop
// (entries beyond cnt carry p=0 and a valid-clamped s).
template <bool RELU>
__global__ __launch_bounds__(256) void edge4_kernel(
    const int* __restrict__ csr, const int* __restrict__ offs,   // [4N+1]
    const float* __restrict__ el4, const float* __restrict__ er4, // [4][N][4]
    const float* __restrict__ feat4,                              // [4][N][64]
    const float* __restrict__ b,                                  // [4][64]
    float* __restrict__ hnext) {
    __shared__ float lds_p[4][64];
    __shared__ int   lds_s[4][16];
    int tid = threadIdx.x;
    int wslot = tid >> 6;
    int lane = tid & 63;
    int d = blockIdx.x * 4 + wslot;
    if (d >= NNODES) return;
    int hp = lane & 3;   // softmax-phase head
    int h2 = lane >> 4;  // PV-phase head (lane = channel)
    int j = lane >> 2;   // softmax-phase edge slot
    float* pslot = &lds_p[wslot][0];
    int* sslot = &lds_s[wslot][0];
    float out = 0.f;
    for (int t = 0; t < NTYPES; t++) {
        int nd = t * NNODES + d;
        int o0 = offs[nd], o1 = offs[nd + 1];
        const float* el = el4 + (size_t)t * NNODES * 4;
        const float* fl = feat4 + (size_t)t * NNODES * 64 + lane;
        float erv = er4[(size_t)nd * 4 + hp];
        float m = -INFINITY, z = 0.f, acc = 0.f;
        for (int base = o0; base < o1; base += 16) {
            int cnt = o1 - base; if (cnt > 16) cnt = 16;
            int idx = base + j; if (idx > o1 - 1) idx = o1 - 1;  // clamp in-bounds
            int s = csr[idx];
            bool valid = j < cnt;
            float e = el[s * 4 + hp] + erv;
            e = e > 0.f ? e : NEG_SLOPE * e;
            if (!valid) e = -INFINITY;
            float cm = e;  // per-head max over the 16 edge slots
            cm = fmaxf(cm, __shfl_xor(cm, 4));
            cm = fmaxf(cm, __shfl_xor(cm, 8));
            cm = fmaxf(cm, __shfl_xor(cm, 16));
            cm = fmaxf(cm, __shfl_xor(cm, 32));
            float mn = fmaxf(m, cm);
            float corr = __expf(m - mn);        // first chunk: exp(-inf)=0
            float p = valid ? __expf(e - mn) : 0.f;
            float zc = p;
            zc += __shfl_xor(zc, 4);
            zc += __shfl_xor(zc, 8);
            zc += __shfl_xor(zc, 16);
            zc += __shfl_xor(zc, 32);
            z = z * corr + zc;
            pslot[(j << 2) | hp] = p;           // stage p (all 64 slots; 0 past cnt)
            if (hp == 0) sslot[j] = s;          // stage s (valid-clamped past cnt)
            acc *= __shfl(corr, h2);
            int rcnt = (cnt + 3) & ~3;          // ceil4: padded slots contribute 0
            for (int k = 0; k < rcnt; k += 4) {
                int s0 = sslot[k + 0], s1 = sslot[k + 1];
                int s2 = sslot[k + 2], s3 = sslot[k + 3];
                float p0 = pslot[((k + 0) << 2) | h2];
                float p1 = pslot[((k + 1) << 2) | h2];
                float p2 = pslot[((k + 2) << 2) | h2];
                float p3 = pslot[((k + 3) << 2) | h2];
                float f0 = fl[s0 * 64], f1 = fl[s1 * 64];
                float f2 = fl[s2 * 64], f3 = fl[s3 * 64];
                acc = fmaf(p0, f0, acc);
                acc = fmaf(p1, f1, acc);
                acc = fmaf(p2, f2, acc);
                acc = fmaf(p3, f3, acc);
            }
            m = mn;
        }
        float z2 = __shfl(z, h2);
        float val = (o1 > o0) ? acc / z2 : 0.f;
        out += val + b[t * 64 + lane];
    }
    if (RELU) out = fmaxf(out, 0.f);
    hnext[(size_t)d * 64 + lane] = out;
}

// ---------------- readout ----------------
__global__ void embed_kernel(const int* __restrict__ gid, const float* __restrict__ h,
                             float* __restrict__ out) {
    int bg = blockIdx.x;
    int lane = threadIdx.x;
    int lo = 0, hi = NNODES;
    while (lo < hi) { int mid = (lo + hi) >> 1; if (gid[mid] < bg) lo = mid + 1; else hi = mid; }
    int start = lo;
    hi = NNODES;
    while (lo < hi) { int mid = (lo + hi) >> 1; if (gid[mid] < bg + 1) lo = mid + 1; else hi = mid; }
    int end = lo;
    float s = 0.f;
    for (int n = start; n < end; n++) s += h[n * 64 + lane];
    out[bg * 64 + lane] = s;
}

__global__ void score_kernel(const float* __restrict__ ow1, const float* __restrict__ ob1,
                             const float* __restrict__ ow2, const float* __restrict__ ob2,
                             const float* __restrict__ embed, float* __restrict__ score) {
    __shared__ float wc[64];
    __shared__ float cst;
    int tid = threadIdx.x;
    if (tid < 64) {
        float s = 0.f;
        for (int j = 0; j < 32; j++) s += ow1[tid * 32 + j] * ow2[j];
        wc[tid] = s;
    }
    if (tid == 64) {
        float s = 0.f;
        for (int j = 0; j < 32; j++) s += ob1[j] * ow2[j];
        cst = s + ob2[0];
    }
    __syncthreads();
    int bg = blockIdx.x * blockDim.x + tid;
    if (bg < NGRAPH) {
        float s = cst;
        for (int c = 0; c < 64; c++) s = fmaf(embed[bg * 64 + c], wc[c], s);
        score[bg] = s;
    }
}

extern "C" void kernel_launch(void* const* d_in, const int* in_sizes, int n_in,
                              void* d_out, int out_size, void* d_ws, size_t ws_size,
                              hipStream_t stream) {
    const int* node_ids  = (const int*)d_in[0];
    const int* graph_ids = (const int*)d_in[1];
    const int* src       = (const int*)d_in[2];
    const int* dst       = (const int*)d_in[3];
    const float* table   = (const float*)d_in[4];
    const float* Wm[3]  = {(const float*)d_in[5],  (const float*)d_in[9],  (const float*)d_in[13]};
    const float* alm[3] = {(const float*)d_in[6],  (const float*)d_in[10], (const float*)d_in[14]};
    const float* arm[3] = {(const float*)d_in[7],  (const float*)d_in[11], (const float*)d_in[15]};
    const float* bm[3]  = {(const float*)d_in[8],  (const float*)d_in[12], (const float*)d_in[16]};
    const float* ow1 = (const float*)d_in[17];
    const float* ob1 = (const float*)d_in[18];
    const float* ow2 = (const float*)d_in[19];
    const float* ob2 = (const float*)d_in[20];

    float* out_embed = (float*)d_out;
    float* out_score = out_embed + NGRAPH * 64;

    const int M = NTYPES * NNODES;
    const int NB = (M + 1023) / 1024;
    const int EDGE_GRID = (NNODES + 3) / 4;

    // ---- workspace (round-10 proved ws_size >= this ~158MB layout) ----
    char* w = (char*)d_ws;
    float* h = (float*)w;      w += 4ull * NNODES * 64;
    float* feat4 = (float*)w;  w += 4ull * NTYPES * NNODES * 64;
    int* csr = (int*)w;        w += 4ull * TE;
    int* offs = (int*)w;       w += 4ull * (M + 16);
    float* el4 = (float*)w;    w += 4ull * NTYPES * NNODES * 4;
    float* er4 = (float*)w;    w += 4ull * NTYPES * NNODES * 4;
    int* cnt = (int*)w;        w += 4ull * M;
    int* fillpos = (int*)w;    w += 4ull * M;
    int* bsum = (int*)w;       w += 4096;

    // ---- CSR build ----
    hipMemsetAsync(cnt, 0, sizeof(int) * M, stream);
    hipMemsetAsync(fillpos, 0, sizeof(int) * M, stream);
    rc_count<<<NRANGE * RCB, 256, 0, stream>>>(dst, cnt);
    scan1_kernel<<<NB, 256, 0, stream>>>(cnt, offs, bsum);
    scan2_kernel<<<1, 512, 0, stream>>>(bsum, NB);
    scan3_kernel<<<(M + 255) / 256, 256, 0, stream>>>(offs, bsum);
    rc_fill<<<NRANGE * RCB, 256, 0, stream>>>(dst, src, offs, fillpos, csr);

    // ---- layer-0 input ----
    gather_kernel<<<(NNODES * 32 + 255) / 256, 256, 0, stream>>>(node_ids, table, h);

    for (int L = 0; L < 3; L++) {
        const int K = (L == 0) ? 32 : 64;
        for (int t = 0; t < NTYPES; t++) {
            const float* Wt = Wm[L] + (size_t)t * K * 64;
            float* ft = feat4 + (size_t)t * NNODES * 64;
            float* elt = el4 + (size_t)t * NNODES * 4;
            float* ert = er4 + (size_t)t * NNODES * 4;
            if (L == 0)
                feat_kernel<32><<<2048, 256, 0, stream>>>(h, Wt, alm[L] + t * 64, arm[L] + t * 64, ft, elt, ert);
            else
                feat_kernel<64><<<2048, 256, 0, stream>>>(h, Wt, alm[L] + t * 64, arm[L] + t * 64, ft, elt, ert);
        }
        if (L < 2)
            edge4_kernel<true><<<EDGE_GRID, 256, 0, stream>>>(csr, offs, el4, er4, feat4, bm[L], h);
        else
            edge4_kernel<false><<<EDGE_GRID, 256, 0, stream>>>(csr, offs, el4, er4, feat4, bm[L], h);
    }

    embed_kernel<<<NGRAPH, 64, 0, stream>>>(graph_ids, h, out_embed);
    score_kernel<<<(NGRAPH + 255) / 256, 256, 0, stream>>>(ow1, ob1, ow2, ob2, out_embed, out_score);
}

// Round 12
// 1237.414 us; speedup vs baseline: 1.3533x; 1.2705x over previous
//
#include <hip/hip_runtime.h>
#include <hip/hip_bf16.h>
#include <cstdint>

// HeteroGAT on MI355X.
// Round-12: feat rewritten as per-layer feat4_kernel — 64-node h tile staged to
// LDS coalesced ONCE, reused for all 4 edge types (round-11 counters: feat was
// ~720us, latency-bound on wave-uniform broadcast loads of h; 12 dispatches ->
// 3, h read once instead of 4x, LDS broadcast feeds the fma chains).
// edge4 (LDS-staged PV, runtime-bounded ceil4 loop) and CSR build unchanged.

#define NNODES 100000
#define NGRAPH 1024
#define NTYPES 4
#define NEDGES 800000
#define NEG_SLOPE 0.2f

#define TE (NTYPES * NEDGES)     // 3.2M edges
#define NRANGE 8
#define RSPAN 12500
#define RCB 128
#define NTILE ((NNODES + 63) / 64)   // 1563 feat tiles

// ---------------- CSR pass 1: range-partitioned per-node count ----------------
__global__ __launch_bounds__(256) void rc_count(const int* __restrict__ dst,
                                                int* __restrict__ cnt) {
    int r = blockIdx.x & 7;
    int m = blockIdx.x >> 3;
    for (int i = m * 256 + threadIdx.x; i < TE; i += RCB * 256) {
        int d = dst[i];
        if (d / RSPAN == r) {
            int t = i / NEDGES;
            atomicAdd(&cnt[t * NNODES + d], 1);
        }
    }
}

// ---------------- scan over T*N counts ----------------
__global__ void scan1_kernel(const int* __restrict__ cnt, int* __restrict__ offs,
                             int* __restrict__ bsum) {
    __shared__ int sh[256];
    const int M = NTYPES * NNODES;
    int base = blockIdx.x * 1024 + threadIdx.x * 4;
    int v[4]; int tot = 0;
#pragma unroll
    for (int j = 0; j < 4; j++) {
        int idx = base + j;
        v[j] = (idx < M) ? cnt[idx] : 0;
        tot += v[j];
    }
    sh[threadIdx.x] = tot;
    __syncthreads();
    for (int off = 1; off < 256; off <<= 1) {
        int add = (threadIdx.x >= off) ? sh[threadIdx.x - off] : 0;
        __syncthreads();
        sh[threadIdx.x] += add;
        __syncthreads();
    }
    int excl = sh[threadIdx.x] - tot;
#pragma unroll
    for (int j = 0; j < 4; j++) {
        int idx = base + j;
        if (idx < M) offs[idx] = excl;
        excl += v[j];
    }
    if (threadIdx.x == 255) bsum[blockIdx.x] = sh[255];
}

__global__ void scan2_kernel(int* __restrict__ bsum, int nb) {
    __shared__ int sh[512];
    int v = (threadIdx.x < nb) ? bsum[threadIdx.x] : 0;
    sh[threadIdx.x] = v;
    __syncthreads();
    for (int off = 1; off < 512; off <<= 1) {
        int add = (threadIdx.x >= off) ? sh[threadIdx.x - off] : 0;
        __syncthreads();
        sh[threadIdx.x] += add;
        __syncthreads();
    }
    if (threadIdx.x < nb) bsum[threadIdx.x] = sh[threadIdx.x] - v;
}

__global__ void scan3_kernel(int* __restrict__ offs, const int* __restrict__ bsum) {
    const int M = NTYPES * NNODES;
    int i = blockIdx.x * 256 + threadIdx.x;
    if (i < M) offs[i] += bsum[i >> 10];
    if (i == 0) offs[M] = TE;
}

// ---------------- CSR pass 2: range-partitioned fill ----------------
__global__ __launch_bounds__(256) void rc_fill(const int* __restrict__ dst,
                                               const int* __restrict__ src,
                                               const int* __restrict__ offs,
                                               int* __restrict__ fillpos,
                                               int* __restrict__ csr) {
    int r = blockIdx.x & 7;
    int m = blockIdx.x >> 3;
    for (int i = m * 256 + threadIdx.x; i < TE; i += RCB * 256) {
        int d = dst[i];
        if (d / RSPAN == r) {
            int t = i / NEDGES;
            int idx = t * NNODES + d;
            int pos = atomicAdd(&fillpos[idx], 1);
            csr[offs[idx] + pos] = src[i];
        }
    }
}

// ---------------- embedding gather ----------------
__global__ void gather_kernel(const int* __restrict__ ids, const float* __restrict__ table,
                              float* __restrict__ h0) {
    int i = blockIdx.x * 256 + threadIdx.x;
    if (i < NNODES * 32) {
        int n = i >> 5, k = i & 31;
        h0[i] = table[ids[n] * 32 + k];
    }
}

// ---------------- feat for ALL 4 types: LDS-staged h tile, reused per type ----
// One block = 64 nodes. Stage h[64][K] to LDS coalesced, then each wave computes
// 16 nodes x 4 types with LDS broadcast reads feeding the fma chains.
template <int K>
__global__ __launch_bounds__(256) void feat4_kernel(
    const float* __restrict__ h, const float* __restrict__ W,   // [T][K][64]
    const float* __restrict__ al, const float* __restrict__ ar, // [T][4][16]
    float* __restrict__ feat4, float* __restrict__ el4, float* __restrict__ er4) {
    __shared__ float hs[64 * K];
    int tid = threadIdx.x;
    int lane = tid & 63;
    int wslot = tid >> 6;
    int n0 = blockIdx.x * 64;
    // stage: coalesced float4 loads; pad dead nodes with zeros
    const int NF4 = 64 * K / 4;
    for (int f = tid; f < NF4; f += 256) {
        int flat = f * 4;
        int node = n0 + flat / K;
        float4 v;
        if (node < NNODES) v = *reinterpret_cast<const float4*>(h + (size_t)n0 * K + flat);
        else               v = float4{0.f, 0.f, 0.f, 0.f};
        *reinterpret_cast<float4*>(&hs[flat]) = v;
    }
    __syncthreads();
    for (int t = 0; t < NTYPES; t++) {
        float Wc[K];
#pragma unroll
        for (int k = 0; k < K; k++) Wc[k] = W[((size_t)t * K + k) * 64 + lane];  // coalesced
        float alr = al[t * 64 + lane];
        float arr = ar[t * 64 + lane];
        float* feat = feat4 + (size_t)t * NNODES * 64;
        float* el = el4 + (size_t)t * NNODES * 4;
        float* er = er4 + (size_t)t * NNODES * 4;
#pragma unroll 4
        for (int i = 0; i < 16; i++) {
            int nl = wslot * 16 + i;
            int n = n0 + nl;
            bool live = n < NNODES;
            const float* hp = &hs[nl * K];
            float acc = 0.f;
#pragma unroll
            for (int k4 = 0; k4 < K; k4 += 4) {
                float4 hv = *reinterpret_cast<const float4*>(hp + k4);  // LDS broadcast
                acc = fmaf(hv.x, Wc[k4 + 0], acc);
                acc = fmaf(hv.y, Wc[k4 + 1], acc);
                acc = fmaf(hv.z, Wc[k4 + 2], acc);
                acc = fmaf(hv.w, Wc[k4 + 3], acc);
            }
            if (live) feat[(size_t)n * 64 + lane] = acc;
            float p = acc * alr, q = acc * arr;
#pragma unroll
            for (int s = 1; s < 16; s <<= 1) {
                p += __shfl_xor(p, s, 64);
                q += __shfl_xor(q, s, 64);
            }
            if (live && (lane & 15) == 0) {
                el[n * 4 + (lane >> 4)] = p;
                er[n * 4 + (lane >> 4)] = q;
            }
        }
    }
}

// ---------------- fused edge pass: all 4 types, one wave per dst --------------
template <bool RELU>
__global__ __launch_bounds__(256) void edge4_kernel(
    const int* __restrict__ csr, const int* __restrict__ offs,   // [4N+1]
    const float* __restrict__ el4, const float* __restrict__ er4, // [4][N][4]
    const float* __restrict__ feat4,                              // [4][N][64]
    const float* __restrict__ b,                                  // [4][64]
    float* __restrict__ hnext) {
    __shared__ float lds_p[4][64];
    __shared__ int   lds_s[4][16];
    int tid = threadIdx.x;
    int wslot = tid >> 6;
    int lane = tid & 63;
    int d = blockIdx.x * 4 + wslot;
    if (d >= NNODES) return;
    int hp = lane & 3;   // softmax-phase head
    int h2 = lane >> 4;  // PV-phase head (lane = channel)
    int j = lane >> 2;   // softmax-phase edge slot
    float* pslot = &lds_p[wslot][0];
    int* sslot = &lds_s[wslot][0];
    float out = 0.f;
    for (int t = 0; t < NTYPES; t++) {
        int nd = t * NNODES + d;
        int o0 = offs[nd], o1 = offs[nd + 1];
        const float* el = el4 + (size_t)t * NNODES * 4;
        const float* fl = feat4 + (size_t)t * NNODES * 64 + lane;
        float erv = er4[(size_t)nd * 4 + hp];
        float m = -INFINITY, z = 0.f, acc = 0.f;
        for (int base = o0; base < o1; base += 16) {
            int cnt = o1 - base; if (cnt > 16) cnt = 16;
            int idx = base + j; if (idx > o1 - 1) idx = o1 - 1;  // clamp in-bounds
            int s = csr[idx];
            bool valid = j < cnt;
            float e = el[s * 4 + hp] + erv;
            e = e > 0.f ? e : NEG_SLOPE * e;
            if (!valid) e = -INFINITY;
            float cm = e;
            cm = fmaxf(cm, __shfl_xor(cm, 4));
            cm = fmaxf(cm, __shfl_xor(cm, 8));
            cm = fmaxf(cm, __shfl_xor(cm, 16));
            cm = fmaxf(cm, __shfl_xor(cm, 32));
            float mn = fmaxf(m, cm);
            float corr = __expf(m - mn);
            float p = valid ? __expf(e - mn) : 0.f;
            float zc = p;
            zc += __shfl_xor(zc, 4);
            zc += __shfl_xor(zc, 8);
            zc += __shfl_xor(zc, 16);
            zc += __shfl_xor(zc, 32);
            z = z * corr + zc;
            pslot[(j << 2) | hp] = p;
            if (hp == 0) sslot[j] = s;
            acc *= __shfl(corr, h2);
            int rcnt = (cnt + 3) & ~3;
            for (int k = 0; k < rcnt; k += 4) {
                int s0 = sslot[k + 0], s1 = sslot[k + 1];
                int s2 = sslot[k + 2], s3 = sslot[k + 3];
                float p0 = pslot[((k + 0) << 2) | h2];
                float p1 = pslot[((k + 1) << 2) | h2];
                float p2 = pslot[((k + 2) << 2) | h2];
                float p3 = pslot[((k + 3) << 2) | h2];
                float f0 = fl[s0 * 64], f1 = fl[s1 * 64];
                float f2 = fl[s2 * 64], f3 = fl[s3 * 64];
                acc = fmaf(p0, f0, acc);
                acc = fmaf(p1, f1, acc);
                acc = fmaf(p2, f2, acc);
                acc = fmaf(p3, f3, acc);
            }
            m = mn;
        }
        float z2 = __shfl(z, h2);
        float val = (o1 > o0) ? acc / z2 : 0.f;
        out += val + b[t * 64 + lane];
    }
    if (RELU) out = fmaxf(out, 0.f);
    hnext[(size_t)d * 64 + lane] = out;
}

// ---------------- readout ----------------
__global__ void embed_kernel(const int* __restrict__ gid, const float* __restrict__ h,
                             float* __restrict__ out) {
    int bg = blockIdx.x;
    int lane = threadIdx.x;
    int lo = 0, hi = NNODES;
    while (lo < hi) { int mid = (lo + hi) >> 1; if (gid[mid] < bg) lo = mid + 1; else hi = mid; }
    int start = lo;
    hi = NNODES;
    while (lo < hi) { int mid = (lo + hi) >> 1; if (gid[mid] < bg + 1) lo = mid + 1; else hi = mid; }
    int end = lo;
    float s = 0.f;
    for (int n = start; n < end; n++) s += h[n * 64 + lane];
    out[bg * 64 + lane] = s;
}

__global__ void score_kernel(const float* __restrict__ ow1, const float* __restrict__ ob1,
                             const float* __restrict__ ow2, const float* __restrict__ ob2,
                             const float* __restrict__ embed, float* __restrict__ score) {
    __shared__ float wc[64];
    __shared__ float cst;
    int tid = threadIdx.x;
    if (tid < 64) {
        float s = 0.f;
        for (int j = 0; j < 32; j++) s += ow1[tid * 32 + j] * ow2[j];
        wc[tid] = s;
    }
    if (tid == 64) {
        float s = 0.f;
        for (int j = 0; j < 32; j++) s += ob1[j] * ow2[j];
        cst = s + ob2[0];
    }
    __syncthreads();
    int bg = blockIdx.x * blockDim.x + tid;
    if (bg < NGRAPH) {
        float s = cst;
        for (int c = 0; c < 64; c++) s = fmaf(embed[bg * 64 + c], wc[c], s);
        score[bg] = s;
    }
}

extern "C" void kernel_launch(void* const* d_in, const int* in_sizes, int n_in,
                              void* d_out, int out_size, void* d_ws, size_t ws_size,
                              hipStream_t stream) {
    const int* node_ids  = (const int*)d_in[0];
    const int* graph_ids = (const int*)d_in[1];
    const int* src       = (const int*)d_in[2];
    const int* dst       = (const int*)d_in[3];
    const float* table   = (const float*)d_in[4];
    const float* Wm[3]  = {(const float*)d_in[5],  (const float*)d_in[9],  (const float*)d_in[13]};
    const float* alm[3] = {(const float*)d_in[6],  (const float*)d_in[10], (const float*)d_in[14]};
    const float* arm[3] = {(const float*)d_in[7],  (const float*)d_in[11], (const float*)d_in[15]};
    const float* bm[3]  = {(const float*)d_in[8],  (const float*)d_in[12], (const float*)d_in[16]};
    const float* ow1 = (const float*)d_in[17];
    const float* ob1 = (const float*)d_in[18];
    const float* ow2 = (const float*)d_in[19];
    const float* ob2 = (const float*)d_in[20];

    float* out_embed = (float*)d_out;
    float* out_score = out_embed + NGRAPH * 64;

    const int M = NTYPES * NNODES;
    const int NB = (M + 1023) / 1024;
    const int EDGE_GRID = (NNODES + 3) / 4;

    // ---- workspace (~158MB; round-10 proved ws_size covers it) ----
    char* w = (char*)d_ws;
    float* h = (float*)w;      w += 4ull * NNODES * 64;
    float* feat4 = (float*)w;  w += 4ull * NTYPES * NNODES * 64;
    int* csr = (int*)w;        w += 4ull * TE;
    int* offs = (int*)w;       w += 4ull * (M + 16);
    float* el4 = (float*)w;    w += 4ull * NTYPES * NNODES * 4;
    float* er4 = (float*)w;    w += 4ull * NTYPES * NNODES * 4;
    int* cnt = (int*)w;        w += 4ull * M;
    int* fillpos = (int*)w;    w += 4ull * M;
    int* bsum = (int*)w;       w += 4096;

    // ---- CSR build ----
    hipMemsetAsync(cnt, 0, sizeof(int) * M, stream);
    hipMemsetAsync(fillpos, 0, sizeof(int) * M, stream);
    rc_count<<<NRANGE * RCB, 256, 0, stream>>>(dst, cnt);
    scan1_kernel<<<NB, 256, 0, stream>>>(cnt, offs, bsum);
    scan2_kernel<<<1, 512, 0, stream>>>(bsum, NB);
    scan3_kernel<<<(M + 255) / 256, 256, 0, stream>>>(offs, bsum);
    rc_fill<<<NRANGE * RCB, 256, 0, stream>>>(dst, src, offs, fillpos, csr);

    // ---- layer-0 input ----
    gather_kernel<<<(NNODES * 32 + 255) / 256, 256, 0, stream>>>(node_ids, table, h);

    for (int L = 0; L < 3; L++) {
        if (L == 0)
            feat4_kernel<32><<<NTILE, 256, 0, stream>>>(h, Wm[L], alm[L], arm[L], feat4, el4, er4);
        else
            feat4_kernel<64><<<NTILE, 256, 0, stream>>>(h, Wm[L], alm[L], arm[L], feat4, el4, er4);
        if (L < 2)
            edge4_kernel<true><<<EDGE_GRID, 256, 0, stream>>>(csr, offs, el4, er4, feat4, bm[L], h);
        else
            edge4_kernel<false><<<EDGE_GRID, 256, 0, stream>>>(csr, offs, el4, er4, feat4, bm[L], h);
    }

    embed_kernel<<<NGRAPH, 64, 0, stream>>>(graph_ids, h, out_embed);
    score_kernel<<<(NGRAPH + 255) / 256, 256, 0, stream>>>(ow1, ob1, ow2, ob2, out_embed, out_score);
}

// Round 14
// 1181.810 us; speedup vs baseline: 1.4170x; 1.0470x over previous
//
#include <hip/hip_runtime.h>
#include <hip/hip_bf16.h>
#include <cstdint>

// HeteroGAT on MI355X.
// Round-13: feat4 stored as bf16 (halves edge4's gather bytes — round-12
// counters: edge4 FETCH 568MB vs ~120MB logical, mixed mem/VALU bound; bf16
// row = 128B fully-coalesced segment). PV accumulates fp32; el/er/h stay fp32.
// CSR build / softmax phase / readout unchanged.

#define NNODES 100000
#define NGRAPH 1024
#define NTYPES 4
#define NEDGES 800000
#define NEG_SLOPE 0.2f

#define TE (NTYPES * NEDGES)     // 3.2M edges
#define NRANGE 8
#define RSPAN 12500
#define RCB 128
#define NTILE ((NNODES + 63) / 64)   // 1563 feat tiles

// ---------------- CSR pass 1: range-partitioned per-node count ----------------
__global__ __launch_bounds__(256) void rc_count(const int* __restrict__ dst,
                                                int* __restrict__ cnt) {
    int r = blockIdx.x & 7;
    int m = blockIdx.x >> 3;
    for (int i = m * 256 + threadIdx.x; i < TE; i += RCB * 256) {
        int d = dst[i];
        if (d / RSPAN == r) {
            int t = i / NEDGES;
            atomicAdd(&cnt[t * NNODES + d], 1);
        }
    }
}

// ---------------- scan over T*N counts ----------------
__global__ void scan1_kernel(const int* __restrict__ cnt, int* __restrict__ offs,
                             int* __restrict__ bsum) {
    __shared__ int sh[256];
    const int M = NTYPES * NNODES;
    int base = blockIdx.x * 1024 + threadIdx.x * 4;
    int v[4]; int tot = 0;
#pragma unroll
    for (int j = 0; j < 4; j++) {
        int idx = base + j;
        v[j] = (idx < M) ? cnt[idx] : 0;
        tot += v[j];
    }
    sh[threadIdx.x] = tot;
    __syncthreads();
    for (int off = 1; off < 256; off <<= 1) {
        int add = (threadIdx.x >= off) ? sh[threadIdx.x - off] : 0;
        __syncthreads();
        sh[threadIdx.x] += add;
        __syncthreads();
    }
    int excl = sh[threadIdx.x] - tot;
#pragma unroll
    for (int j = 0; j < 4; j++) {
        int idx = base + j;
        if (idx < M) offs[idx] = excl;
        excl += v[j];
    }
    if (threadIdx.x == 255) bsum[blockIdx.x] = sh[255];
}

__global__ void scan2_kernel(int* __restrict__ bsum, int nb) {
    __shared__ int sh[512];
    int v = (threadIdx.x < nb) ? bsum[threadIdx.x] : 0;
    sh[threadIdx.x] = v;
    __syncthreads();
    for (int off = 1; off < 512; off <<= 1) {
        int add = (threadIdx.x >= off) ? sh[threadIdx.x - off] : 0;
        __syncthreads();
        sh[threadIdx.x] += add;
        __syncthreads();
    }
    if (threadIdx.x < nb) bsum[threadIdx.x] = sh[threadIdx.x] - v;
}

__global__ void scan3_kernel(int* __restrict__ offs, const int* __restrict__ bsum) {
    const int M = NTYPES * NNODES;
    int i = blockIdx.x * 256 + threadIdx.x;
    if (i < M) offs[i] += bsum[i >> 10];
    if (i == 0) offs[M] = TE;
}

// ---------------- CSR pass 2: range-partitioned fill ----------------
__global__ __launch_bounds__(256) void rc_fill(const int* __restrict__ dst,
                                               const int* __restrict__ src,
                                               const int* __restrict__ offs,
                                               int* __restrict__ fillpos,
                                               int* __restrict__ csr) {
    int r = blockIdx.x & 7;
    int m = blockIdx.x >> 3;
    for (int i = m * 256 + threadIdx.x; i < TE; i += RCB * 256) {
        int d = dst[i];
        if (d / RSPAN == r) {
            int t = i / NEDGES;
            int idx = t * NNODES + d;
            int pos = atomicAdd(&fillpos[idx], 1);
            csr[offs[idx] + pos] = src[i];
        }
    }
}

// ---------------- embedding gather ----------------
__global__ void gather_kernel(const int* __restrict__ ids, const float* __restrict__ table,
                              float* __restrict__ h0) {
    int i = blockIdx.x * 256 + threadIdx.x;
    if (i < NNODES * 32) {
        int n = i >> 5, k = i & 31;
        h0[i] = table[ids[n] * 32 + k];
    }
}

// ---------------- feat for ALL 4 types: LDS-staged h tile, bf16 output --------
template <int K>
__global__ __launch_bounds__(256) void feat4_kernel(
    const float* __restrict__ h, const float* __restrict__ W,   // [T][K][64]
    const float* __restrict__ al, const float* __restrict__ ar, // [T][4][16]
    __hip_bfloat16* __restrict__ feat4, float* __restrict__ el4,
    float* __restrict__ er4) {
    __shared__ float hs[64 * K];
    int tid = threadIdx.x;
    int lane = tid & 63;
    int wslot = tid >> 6;
    int n0 = blockIdx.x * 64;
    const int NF4 = 64 * K / 4;
    for (int f = tid; f < NF4; f += 256) {
        int flat = f * 4;
        int node = n0 + flat / K;
        float4 v;
        if (node < NNODES) v = *reinterpret_cast<const float4*>(h + (size_t)n0 * K + flat);
        else               v = float4{0.f, 0.f, 0.f, 0.f};
        *reinterpret_cast<float4*>(&hs[flat]) = v;
    }
    __syncthreads();
    for (int t = 0; t < NTYPES; t++) {
        float Wc[K];
#pragma unroll
        for (int k = 0; k < K; k++) Wc[k] = W[((size_t)t * K + k) * 64 + lane];
        float alr = al[t * 64 + lane];
        float arr = ar[t * 64 + lane];
        __hip_bfloat16* feat = feat4 + (size_t)t * NNODES * 64;
        float* el = el4 + (size_t)t * NNODES * 4;
        float* er = er4 + (size_t)t * NNODES * 4;
#pragma unroll 4
        for (int i = 0; i < 16; i++) {
            int nl = wslot * 16 + i;
            int n = n0 + nl;
            bool live = n < NNODES;
            const float* hp = &hs[nl * K];
            float acc = 0.f;
#pragma unroll
            for (int k4 = 0; k4 < K; k4 += 4) {
                float4 hv = *reinterpret_cast<const float4*>(hp + k4);
                acc = fmaf(hv.x, Wc[k4 + 0], acc);
                acc = fmaf(hv.y, Wc[k4 + 1], acc);
                acc = fmaf(hv.z, Wc[k4 + 2], acc);
                acc = fmaf(hv.w, Wc[k4 + 3], acc);
            }
            if (live) feat[(size_t)n * 64 + lane] = __float2bfloat16(acc);
            float p = acc * alr, q = acc * arr;
#pragma unroll
            for (int s = 1; s < 16; s <<= 1) {
                p += __shfl_xor(p, s, 64);
                q += __shfl_xor(q, s, 64);
            }
            if (live && (lane & 15) == 0) {
                el[n * 4 + (lane >> 4)] = p;
                er[n * 4 + (lane >> 4)] = q;
            }
        }
    }
}

// ---------------- fused edge pass: all 4 types, one wave per dst --------------
template <bool RELU>
__global__ __launch_bounds__(256) void edge4_kernel(
    const int* __restrict__ csr, const int* __restrict__ offs,    // [4N+1]
    const float* __restrict__ el4, const float* __restrict__ er4,  // [4][N][4]
    const __hip_bfloat16* __restrict__ feat4,                      // [4][N][64] bf16
    const float* __restrict__ b,                                   // [4][64]
    float* __restrict__ hnext) {
    __shared__ float lds_p[4][64];
    __shared__ int   lds_s[4][16];
    int tid = threadIdx.x;
    int wslot = tid >> 6;
    int lane = tid & 63;
    int d = blockIdx.x * 4 + wslot;
    if (d >= NNODES) return;
    int hp = lane & 3;   // softmax-phase head
    int h2 = lane >> 4;  // PV-phase head (lane = channel)
    int j = lane >> 2;   // softmax-phase edge slot
    float* pslot = &lds_p[wslot][0];
    int* sslot = &lds_s[wslot][0];
    float out = 0.f;
    for (int t = 0; t < NTYPES; t++) {
        int nd = t * NNODES + d;
        int o0 = offs[nd], o1 = offs[nd + 1];
        const float* el = el4 + (size_t)t * NNODES * 4;
        const __hip_bfloat16* fl = feat4 + (size_t)t * NNODES * 64 + lane;
        float erv = er4[(size_t)nd * 4 + hp];
        float m = -INFINITY, z = 0.f, acc = 0.f;
        for (int base = o0; base < o1; base += 16) {
            int cnt = o1 - base; if (cnt > 16) cnt = 16;
            int idx = base + j; if (idx > o1 - 1) idx = o1 - 1;  // clamp in-bounds
            int s = csr[idx];
            bool valid = j < cnt;
            float e = el[s * 4 + hp] + erv;
            e = e > 0.f ? e : NEG_SLOPE * e;
            if (!valid) e = -INFINITY;
            float cm = e;
            cm = fmaxf(cm, __shfl_xor(cm, 4));
            cm = fmaxf(cm, __shfl_xor(cm, 8));
            cm = fmaxf(cm, __shfl_xor(cm, 16));
            cm = fmaxf(cm, __shfl_xor(cm, 32));
            float mn = fmaxf(m, cm);
            float corr = __expf(m - mn);
            float p = valid ? __expf(e - mn) : 0.f;
            float zc = p;
            zc += __shfl_xor(zc, 4);
            zc += __shfl_xor(zc, 8);
            zc += __shfl_xor(zc, 16);
            zc += __shfl_xor(zc, 32);
            z = z * corr + zc;
            pslot[(j << 2) | hp] = p;
            if (hp == 0) sslot[j] = s;
            acc *= __shfl(corr, h2);
            int rcnt = (cnt + 3) & ~3;
            for (int k = 0; k < rcnt; k += 4) {
                int s0 = sslot[k + 0], s1 = sslot[k + 1];
                int s2 = sslot[k + 2], s3 = sslot[k + 3];
                float p0 = pslot[((k + 0) << 2) | h2];
                float p1 = pslot[((k + 1) << 2) | h2];
                float p2 = pslot[((k + 2) << 2) | h2];
                float p3 = pslot[((k + 3) << 2) | h2];
                float f0 = __bfloat162float(fl[(size_t)s0 * 64]);
                float f1 = __bfloat162float(fl[(size_t)s1 * 64]);
                float f2 = __bfloat162float(fl[(size_t)s2 * 64]);
                float f3 = __bfloat162float(fl[(size_t)s3 * 64]);
                acc = fmaf(p0, f0, acc);
                acc = fmaf(p1, f1, acc);
                acc = fmaf(p2, f2, acc);
                acc = fmaf(p3, f3, acc);
            }
            m = mn;
        }
        float z2 = __shfl(z, h2);
        float val = (o1 > o0) ? acc / z2 : 0.f;
        out += val + b[t * 64 + lane];
    }
    if (RELU) out = fmaxf(out, 0.f);
    hnext[(size_t)d * 64 + lane] = out;
}

// ---------------- readout ----------------
__global__ void embed_kernel(const int* __restrict__ gid, const float* __restrict__ h,
                             float* __restrict__ out) {
    int bg = blockIdx.x;
    int lane = threadIdx.x;
    int lo = 0, hi = NNODES;
    while (lo < hi) { int mid = (lo + hi) >> 1; if (gid[mid] < bg) lo = mid + 1; else hi = mid; }
    int start = lo;
    hi = NNODES;
    while (lo < hi) { int mid = (lo + hi) >> 1; if (gid[mid] < bg + 1) lo = mid + 1; else hi = mid; }
    int end = lo;
    float s = 0.f;
    for (int n = start; n < end; n++) s += h[n * 64 + lane];
    out[bg * 64 + lane] = s;
}

__global__ void score_kernel(const float* __restrict__ ow1, const float* __restrict__ ob1,
                             const float* __restrict__ ow2, const float* __restrict__ ob2,
                             const float* __restrict__ embed, float* __restrict__ score) {
    __shared__ float wc[64];
    __shared__ float cst;
    int tid = threadIdx.x;
    if (tid < 64) {
        float s = 0.f;
        for (int j = 0; j < 32; j++) s += ow1[tid * 32 + j] * ow2[j];
        wc[tid] = s;
    }
    if (tid == 64) {
        float s = 0.f;
        for (int j = 0; j < 32; j++) s += ob1[j] * ow2[j];
        cst = s + ob2[0];
    }
    __syncthreads();
    int bg = blockIdx.x * blockDim.x + tid;
    if (bg < NGRAPH) {
        float s = cst;
        for (int c = 0; c < 64; c++) s = fmaf(embed[bg * 64 + c], wc[c], s);
        score[bg] = s;
    }
}

extern "C" void kernel_launch(void* const* d_in, const int* in_sizes, int n_in,
                              void* d_out, int out_size, void* d_ws, size_t ws_size,
                              hipStream_t stream) {
    const int* node_ids  = (const int*)d_in[0];
    const int* graph_ids = (const int*)d_in[1];
    const int* src       = (const int*)d_in[2];
    const int* dst       = (const int*)d_in[3];
    const float* table   = (const float*)d_in[4];
    const float* Wm[3]  = {(const float*)d_in[5],  (const float*)d_in[9],  (const float*)d_in[13]};
    const float* alm[3] = {(const float*)d_in[6],  (const float*)d_in[10], (const float*)d_in[14]};
    const float* arm[3] = {(const float*)d_in[7],  (const float*)d_in[11], (const float*)d_in[15]};
    const float* bm[3]  = {(const float*)d_in[8],  (const float*)d_in[12], (const float*)d_in[16]};
    const float* ow1 = (const float*)d_in[17];
    const float* ob1 = (const float*)d_in[18];
    const float* ow2 = (const float*)d_in[19];
    const float* ob2 = (const float*)d_in[20];

    float* out_embed = (float*)d_out;
    float* out_score = out_embed + NGRAPH * 64;

    const int M = NTYPES * NNODES;
    const int NB = (M + 1023) / 1024;
    const int EDGE_GRID = (NNODES + 3) / 4;

    // ---- workspace (~107MB now: feat4 is bf16) ----
    char* w = (char*)d_ws;
    float* h = (float*)w;              w += 4ull * NNODES * 64;
    __hip_bfloat16* feat4 = (__hip_bfloat16*)w;  w += 2ull * NTYPES * NNODES * 64;
    int* csr = (int*)w;                w += 4ull * TE;
    int* offs = (int*)w;               w += 4ull * (M + 16);
    float* el4 = (float*)w;            w += 4ull * NTYPES * NNODES * 4;
    float* er4 = (float*)w;            w += 4ull * NTYPES * NNODES * 4;
    int* cnt = (int*)w;                w += 4ull * M;
    int* fillpos = (int*)w;            w += 4ull * M;
    int* bsum = (int*)w;               w += 4096;

    // ---- CSR build ----
    hipMemsetAsync(cnt, 0, sizeof(int) * M, stream);
    hipMemsetAsync(fillpos, 0, sizeof(int) * M, stream);
    rc_count<<<NRANGE * RCB, 256, 0, stream>>>(dst, cnt);
    scan1_kernel<<<NB, 256, 0, stream>>>(cnt, offs, bsum);
    scan2_kernel<<<1, 512, 0, stream>>>(bsum, NB);
    scan3_kernel<<<(M + 255) / 256, 256, 0, stream>>>(offs, bsum);
    rc_fill<<<NRANGE * RCB, 256, 0, stream>>>(dst, src, offs, fillpos, csr);

    // ---- layer-0 input ----
    gather_kernel<<<(NNODES * 32 + 255) / 256, 256, 0, stream>>>(node_ids, table, h);

    for (int L = 0; L < 3; L++) {
        if (L == 0)
            feat4_kernel<32><<<NTILE, 256, 0, stream>>>(h, Wm[L], alm[L], arm[L], feat4, el4, er4);
        else
            feat4_kernel<64><<<NTILE, 256, 0, stream>>>(h, Wm[L], alm[L], arm[L], feat4, el4, er4);
        if (L < 2)
            edge4_kernel<true><<<EDGE_GRID, 256, 0, stream>>>(csr, offs, el4, er4, feat4, bm[L], h);
        else
            edge4_kernel<false><<<EDGE_GRID, 256, 0, stream>>>(csr, offs, el4, er4, feat4, bm[L], h);
    }

    embed_kernel<<<NGRAPH, 64, 0, stream>>>(graph_ids, h, out_embed);
    score_kernel<<<(NGRAPH + 255) / 256, 256, 0, stream>>>(ow1, ob1, ow2, ob2, out_embed, out_score);
}